// Round 1
// baseline (24.246 us; speedup 1.0000x reference)
//
#include <hip/hip_runtime.h>
#include <cstddef>

// Problem constants (from reference setup_inputs)
#define BB      16
#define TDIM    256
#define DDIM    512
#define LDIM    32
#define TROWS   16      // t-rows per block
#define CD      128     // D-chunk staged in LDS
#define NCHUNK  (DDIM / CD)
#define EPSV    1e-8f

// Block: 256 threads = (32 l) x (8 tg), each thread owns 2 t-rows -> 2 outputs.
// Grid: BB * (TDIM/TROWS) = 16 * 16 = 256 blocks (one b x 16-row tile each).
__global__ __launch_bounds__(256, 1) void fullmatch_kernel(
    const float* __restrict__ v1,       // [B,T,D]
    const float* __restrict__ v1_mask,  // [B,T]
    const float* __restrict__ v2,       // [B,D]
    const float* __restrict__ w,        // [L,D]
    float* __restrict__ out)            // [B,T,L]
{
    const int tid  = threadIdx.x;
    const int b    = blockIdx.x >> 4;   // TDIM/TROWS = 16 t-groups per b
    const int tgrp = blockIdx.x & 15;
    const int t0b  = tgrp * TROWS;

    const int l  = tid & 31;
    const int tg = tid >> 5;            // 0..7
    const int t0 = t0b + tg * 2;

    __shared__ float v1s[TROWS][CD];     // 8 KB, broadcast reads (no conflict)
    __shared__ float ws[LDIM][CD + 1];   // 16.5 KB, +1 pad -> bank (l+dd)%32, conflict-free
    __shared__ float hs[LDIM][CD + 1];   // 16.5 KB
    __shared__ float n2s[LDIM];
    __shared__ float red[8][LDIM];

    const float* v2b = v2 + (size_t)b * DDIM;

    // ---- n2[l] = sqrt(sum_d v2[b,d]^2 * w[l,d]^2), once per block ----
    {
        const float* wrow = w + (size_t)l * DDIM + tg * 64;
        const float* vseg = v2b + tg * 64;
        float acc = 0.f;
        #pragma unroll 8
        for (int i = 0; i < 64; ++i) {
            const float wv = wrow[i];
            const float vv = vseg[i];
            acc = fmaf(wv * wv, vv * vv, acc);
        }
        red[tg][l] = acc;
    }
    __syncthreads();
    if (tid < LDIM) {
        float s = 0.f;
        #pragma unroll
        for (int i = 0; i < 8; ++i) s += red[i][tid];
        n2s[tid] = sqrtf(s);
    }
    // (chunk-loop __syncthreads below makes n2s visible before epilogue)

    float num0 = 0.f, num1 = 0.f, n1a = 0.f, n1b = 0.f;

    for (int c = 0; c < NCHUNK; ++c) {
        const int d0 = c * CD;
        __syncthreads();   // protect LDS from previous iteration's readers

        // stage masked v1 tile: 16 rows x 128 cols = 512 float4, 2 per thread (coalesced)
        #pragma unroll
        for (int k = 0; k < 2; ++k) {
            const int f = tid + k * 256;
            const int r = f >> 5;        // row 0..15
            const int q = f & 31;        // float4 col 0..31
            const float4 val = *(const float4*)(v1 + (size_t)(b * TDIM + t0b + r) * DDIM + d0 + q * 4);
            const float  mk  = v1_mask[b * TDIM + t0b + r];
            float4 o;
            o.x = val.x * mk; o.y = val.y * mk; o.z = val.z * mk; o.w = val.w * mk;
            *(float4*)(&v1s[r][q * 4]) = o;
        }
        // stage w2 and h = w2 * v2: 32 rows x 128 cols, 4 float4 per thread (coalesced global)
        // scalar LDS stores because of the +1 pad (4-way write conflict, small fraction of LDS ops)
        #pragma unroll
        for (int k = 0; k < 4; ++k) {
            const int f = tid + k * 256;
            const int r = f >> 5;        // l row 0..31
            const int q = f & 31;
            const float4 wv = *(const float4*)(w + (size_t)r * DDIM + d0 + q * 4);
            const float4 vv = *(const float4*)(v2b + d0 + q * 4);
            const float w2x = wv.x * wv.x, w2y = wv.y * wv.y, w2z = wv.z * wv.z, w2w = wv.w * wv.w;
            ws[r][q*4+0] = w2x;        ws[r][q*4+1] = w2y;
            ws[r][q*4+2] = w2z;        ws[r][q*4+3] = w2w;
            hs[r][q*4+0] = w2x * vv.x; hs[r][q*4+1] = w2y * vv.y;
            hs[r][q*4+2] = w2z * vv.z; hs[r][q*4+3] = w2w * vv.w;
        }
        __syncthreads();

        const float* __restrict__ a0p = &v1s[tg * 2][0];
        const float* __restrict__ a1p = &v1s[tg * 2 + 1][0];
        const float* __restrict__ wp  = &ws[l][0];
        const float* __restrict__ hp  = &hs[l][0];

        #pragma unroll 8
        for (int dd = 0; dd < CD; dd += 4) {
            const float4 a0 = *(const float4*)(a0p + dd);   // ds_read_b128, broadcast
            const float4 a1 = *(const float4*)(a1p + dd);
            const float w0 = wp[dd+0], w1 = wp[dd+1], w2_ = wp[dd+2], w3 = wp[dd+3];
            const float h0 = hp[dd+0], h1 = hp[dd+1], h2  = hp[dd+2], h3 = hp[dd+3];

            num0 = fmaf(a0.x, h0, num0);
            num0 = fmaf(a0.y, h1, num0);
            num0 = fmaf(a0.z, h2, num0);
            num0 = fmaf(a0.w, h3, num0);
            num1 = fmaf(a1.x, h0, num1);
            num1 = fmaf(a1.y, h1, num1);
            num1 = fmaf(a1.z, h2, num1);
            num1 = fmaf(a1.w, h3, num1);

            n1a = fmaf(a0.x * a0.x, w0,  n1a);
            n1a = fmaf(a0.y * a0.y, w1,  n1a);
            n1a = fmaf(a0.z * a0.z, w2_, n1a);
            n1a = fmaf(a0.w * a0.w, w3,  n1a);
            n1b = fmaf(a1.x * a1.x, w0,  n1b);
            n1b = fmaf(a1.y * a1.y, w1,  n1b);
            n1b = fmaf(a1.z * a1.z, w2_, n1b);
            n1b = fmaf(a1.w * a1.w, w3,  n1b);
        }
    }

    const float n2v = n2s[l];
    const float den0 = fmaxf(sqrtf(n1a) * n2v, EPSV);
    const float den1 = fmaxf(sqrtf(n1b) * n2v, EPSV);
    out[(size_t)(b * TDIM + t0)     * LDIM + l] = num0 / den0;
    out[(size_t)(b * TDIM + t0 + 1) * LDIM + l] = num1 / den1;
}

extern "C" void kernel_launch(void* const* d_in, const int* in_sizes, int n_in,
                              void* d_out, int out_size, void* d_ws, size_t ws_size,
                              hipStream_t stream) {
    const float* v1      = (const float*)d_in[0];
    const float* v1_mask = (const float*)d_in[1];
    const float* v2      = (const float*)d_in[2];
    const float* w       = (const float*)d_in[3];
    float* out           = (float*)d_out;

    const dim3 grid(BB * (TDIM / TROWS));   // 256 blocks
    const dim3 block(256);
    fullmatch_kernel<<<grid, block, 0, stream>>>(v1, v1_mask, v2, w, out);
}

// Round 2
// 21.732 us; speedup vs baseline: 1.1157x; 1.1157x over previous
//
#include <hip/hip_runtime.h>
#include <cstddef>

// Problem constants (from reference setup_inputs)
#define BB      16
#define TDIM    256
#define DDIM    512
#define LDIM    32
#define TROWS   16
#define NTHREADS 1024
#define EPSV    1e-8f

// Block: 1024 threads = (32 l) x (32 dq). Thread (l,dq) owns a 16-element
// D-slice (d = dq*4 + j*128, j=0..3) of w^2[l,:] and h[l,:]=w^2*v2[b,:] in
// registers, accumulates partial num/n1^2 for all 16 t-rows, then a 5-step
// shfl_xor butterfly over dq finishes the dot products. No w/h LDS traffic,
// no inner-loop barriers. Grid = 16 b x 16 t-tiles = 256 blocks, 16 waves each.
__global__ __launch_bounds__(NTHREADS, 1) void fullmatch_kernel(
    const float* __restrict__ v1,       // [B,T,D]
    const float* __restrict__ v1_mask,  // [B,T]
    const float* __restrict__ v2,       // [B,D]
    const float* __restrict__ w,        // [L,D]
    float* __restrict__ out)            // [B,T,L]
{
    const int tid  = threadIdx.x;
    const int b    = blockIdx.x >> 4;
    const int tgrp = blockIdx.x & 15;
    const int t0b  = tgrp * TROWS;

    const int dq = tid & 31;   // D-slice selector
    const int l  = tid >> 5;   // perspective 0..31

    __shared__ float v1s[TROWS][DDIM];    // 32 KB masked v1 tile
    __shared__ float otile[TROWS][LDIM];  // 2 KB output staging

    // ---- per-thread w2 / h register slices + n2 partial (pure register work,
    //      global loads overlap the v1 staging below) ----
    float4 w2r[4], hr[4];
    float n2p = 0.f;
    {
        const float* __restrict__ wrow = w  + (size_t)l * DDIM;
        const float* __restrict__ v2b  = v2 + (size_t)b * DDIM;
        #pragma unroll
        for (int j = 0; j < 4; ++j) {
            const int d = dq * 4 + j * 128;       // lanes dq contiguous -> coalesced
            const float4 wv = *(const float4*)(wrow + d);
            const float4 vv = *(const float4*)(v2b + d);
            float4 w2;
            w2.x = wv.x * wv.x; w2.y = wv.y * wv.y;
            w2.z = wv.z * wv.z; w2.w = wv.w * wv.w;
            w2r[j] = w2;
            float4 h;
            h.x = w2.x * vv.x; h.y = w2.y * vv.y;
            h.z = w2.z * vv.z; h.w = w2.w * vv.w;
            hr[j] = h;
            n2p = fmaf(h.x, vv.x, n2p);
            n2p = fmaf(h.y, vv.y, n2p);
            n2p = fmaf(h.z, vv.z, n2p);
            n2p = fmaf(h.w, vv.w, n2p);
        }
    }

    // ---- stage masked v1 tile: 16 rows x 512 = 2048 float4, 2 per thread ----
    #pragma unroll
    for (int k = 0; k < 2; ++k) {
        const int f = tid + k * NTHREADS;
        const int r = f >> 7;        // t-row 0..15 (128 float4 per row)
        const int q = f & 127;       // float4 col
        const float4 val = *(const float4*)(v1 + (size_t)(b * TDIM + t0b + r) * DDIM + q * 4);
        const float  mk  = v1_mask[b * TDIM + t0b + r];
        float4 o;
        o.x = val.x * mk; o.y = val.y * mk; o.z = val.z * mk; o.w = val.w * mk;
        *(float4*)(&v1s[r][q * 4]) = o;
    }
    __syncthreads();

    // ---- main accumulation: all registers + broadcast b128 LDS reads ----
    float accN[TROWS], accD[TROWS];
    #pragma unroll
    for (int t = 0; t < TROWS; ++t) { accN[t] = 0.f; accD[t] = 0.f; }

    #pragma unroll
    for (int j = 0; j < 4; ++j) {
        const float4 w2 = w2r[j];
        const float4 h  = hr[j];
        const float* __restrict__ base = &v1s[0][dq * 4 + j * 128];
        #pragma unroll
        for (int t = 0; t < TROWS; ++t) {
            const float4 a = *(const float4*)(base + t * DDIM);  // 2-way broadcast b128
            accN[t] = fmaf(a.x, h.x, accN[t]);
            accN[t] = fmaf(a.y, h.y, accN[t]);
            accN[t] = fmaf(a.z, h.z, accN[t]);
            accN[t] = fmaf(a.w, h.w, accN[t]);
            accD[t] = fmaf(a.x * a.x, w2.x, accD[t]);
            accD[t] = fmaf(a.y * a.y, w2.y, accD[t]);
            accD[t] = fmaf(a.z * a.z, w2.z, accD[t]);
            accD[t] = fmaf(a.w * a.w, w2.w, accD[t]);
        }
    }

    // ---- butterfly reduce over the 32 dq lanes (masks 1..16 stay in-half) ----
    #pragma unroll
    for (int m = 16; m >= 1; m >>= 1) {
        n2p += __shfl_xor(n2p, m, 64);
        #pragma unroll
        for (int t = 0; t < TROWS; ++t) {
            accN[t] += __shfl_xor(accN[t], m, 64);
            accD[t] += __shfl_xor(accD[t], m, 64);
        }
    }

    if (dq == 0) {
        const float n2v = sqrtf(n2p);
        #pragma unroll
        for (int t = 0; t < TROWS; ++t) {
            const float den = fmaxf(sqrtf(accD[t]) * n2v, EPSV);
            otile[t][l] = accN[t] / den;
        }
    }
    __syncthreads();

    // ---- coalesced output store: 16x32 tile is contiguous in out ----
    if (tid < (TROWS * LDIM) / 4) {
        const size_t base = (size_t)(b * TDIM + t0b) * LDIM;
        *(float4*)(out + base + tid * 4) = *(const float4*)(&otile[0][0] + tid * 4);
    }
}

extern "C" void kernel_launch(void* const* d_in, const int* in_sizes, int n_in,
                              void* d_out, int out_size, void* d_ws, size_t ws_size,
                              hipStream_t stream) {
    const float* v1      = (const float*)d_in[0];
    const float* v1_mask = (const float*)d_in[1];
    const float* v2      = (const float*)d_in[2];
    const float* w       = (const float*)d_in[3];
    float* out           = (float*)d_out;

    const dim3 grid(BB * (TDIM / TROWS));   // 256 blocks, one per CU
    const dim3 block(NTHREADS);
    fullmatch_kernel<<<grid, block, 0, stream>>>(v1, v1_mask, v2, w, out);
}

// Round 3
// 21.255 us; speedup vs baseline: 1.1407x; 1.0224x over previous
//
#include <hip/hip_runtime.h>
#include <cstddef>

#define EPSV 1e-8f

__device__ __forceinline__ float rdlane(float x, int s) {
    return __int_as_float(__builtin_amdgcn_readlane(__float_as_int(x), s));
}

#define GLD16(gp, lp) \
    __builtin_amdgcn_global_load_lds((const __attribute__((address_space(1))) void*)(gp), \
                                     (__attribute__((address_space(3))) void*)(lp), 16, 0, 0)

// Grid: 256 blocks (XCD-swizzled). Block: 256 thr = 4 waves.
// Wave = 64 t-lanes x 1 l-pair (l, l+16): w2/h are wave-uniform -> v_readlane
// broadcast from a 32-VGPR distributed copy. No inner-loop cross-lane reduce.
// v1 tile 64t x 512k staged in 4 chunks of 128k, double-buffered via
// global_load_lds (linear LDS dest, pre-swizzled global src; read XOR-swizzled).
__global__ __launch_bounds__(256, 1) void fullmatch_kernel(
    const float* __restrict__ v1,       // [16,256,512]
    const float* __restrict__ v1_mask,  // [16,256]
    const float* __restrict__ v2,       // [16,512]
    const float* __restrict__ w,        // [32,512]
    float* __restrict__ out)            // [16,256,32]
{
    const int tid  = threadIdx.x;
    const int lane = tid & 63;
    const int wv   = tid >> 6;          // 0..3

    // XCD swizzle: blocks sharing a v1 tile (same tileg, 4 l-groups) -> same XCD L2.
    const int bid   = blockIdx.x;
    const int xcd   = bid & 7;
    const int slot  = bid >> 3;          // 0..31
    const int tileg = xcd * 8 + (slot >> 2);  // 0..63 = 16b x 4tc
    const int lg    = slot & 3;
    const int b  = tileg >> 2;
    const int tc = tileg & 3;
    const int t0 = tc * 64;
    const int p  = lg * 4 + wv;          // l-pair id 0..15 -> l = p, p+16
    const int t  = t0 + lane;

    __shared__ float v1s[2][64][128];    // 64 KB double-buffered K-chunk

    const size_t v1base = (size_t)(b * 256 + t0) * 512;

    // ---- issue chunk 0 staging (async global->LDS, overlaps reg prep) ----
    #pragma unroll
    for (int j = 0; j < 8; ++j) {
        const int r0 = (wv * 8 + j) * 2;          // 2 rows per issue
        const int r  = r0 + (lane >> 5);
        const int c4 = (lane & 31) ^ (r & 31);    // inverse-swizzled source col
        GLD16(v1 + v1base + (size_t)r * 512 + c4 * 4, &v1s[0][r0][0]);
    }

    // ---- per-wave w2/h register slices (distributed over 64 lanes) + n2 ----
    float4 w2A[2], w2B[2], hA[2], hB[2];
    float n2pA = 0.f, n2pB = 0.f;
    {
        const float* __restrict__ v2b = v2 + (size_t)b * 512;
        const float* __restrict__ wAp = w + (size_t)p * 512;
        const float* __restrict__ wBp = w + (size_t)(p + 16) * 512;
        #pragma unroll
        for (int q = 0; q < 2; ++q) {
            const int k4 = q * 64 + lane;
            const float4 wa = *(const float4*)(wAp + k4 * 4);
            const float4 wb = *(const float4*)(wBp + k4 * 4);
            const float4 vv = *(const float4*)(v2b + k4 * 4);
            float4 sa, sb, ha, hb;
            sa.x = wa.x*wa.x; sa.y = wa.y*wa.y; sa.z = wa.z*wa.z; sa.w = wa.w*wa.w;
            sb.x = wb.x*wb.x; sb.y = wb.y*wb.y; sb.z = wb.z*wb.z; sb.w = wb.w*wb.w;
            ha.x = sa.x*vv.x; ha.y = sa.y*vv.y; ha.z = sa.z*vv.z; ha.w = sa.w*vv.w;
            hb.x = sb.x*vv.x; hb.y = sb.y*vv.y; hb.z = sb.z*vv.z; hb.w = sb.w*vv.w;
            w2A[q] = sa; w2B[q] = sb; hA[q] = ha; hB[q] = hb;
            n2pA += ha.x*vv.x + ha.y*vv.y + ha.z*vv.z + ha.w*vv.w;
            n2pB += hb.x*vv.x + hb.y*vv.y + hb.z*vv.z + hb.w*vv.w;
        }
    }
    // one-time 64-lane butterfly for n2 (12 cross-lane ops total)
    #pragma unroll
    for (int m = 32; m >= 1; m >>= 1) {
        n2pA += __shfl_xor(n2pA, m, 64);
        n2pB += __shfl_xor(n2pB, m, 64);
    }
    const float n2vA = sqrtf(n2pA);
    const float n2vB = sqrtf(n2pB);
    const float mk   = v1_mask[b * 256 + t];

    float accNA = 0.f, accNB = 0.f, accDA = 0.f, accDB = 0.f;

    #pragma unroll
    for (int c = 0; c < 4; ++c) {
        __syncthreads();   // buf[c&1] staged (vmcnt drained); prev readers done (WAR)
        if (c < 3) {
            // issue chunk c+1 into the other buffer; overlaps compute below
            #pragma unroll
            for (int j = 0; j < 8; ++j) {
                const int r0 = (wv * 8 + j) * 2;
                const int r  = r0 + (lane >> 5);
                const int c4 = (lane & 31) ^ (r & 31);
                GLD16(v1 + v1base + (size_t)r * 512 + (c + 1) * 128 + c4 * 4,
                      &v1s[(c + 1) & 1][r0][0]);
            }
        }
        const float* __restrict__ row = &v1s[c & 1][lane][0];
        const int lm = lane & 31;
        #pragma unroll 8
        for (int s = 0; s < 32; ++s) {
            const float4 a = *(const float4*)(row + ((s ^ lm) << 2));
            const int li = ((c & 1) << 5) + s;   // lane holding k4 = c*32+s
            // wave-uniform broadcasts of w2/h (VALU pipe, not LDS)
            const float wax = rdlane(w2A[c >> 1].x, li);
            const float way = rdlane(w2A[c >> 1].y, li);
            const float waz = rdlane(w2A[c >> 1].z, li);
            const float waw = rdlane(w2A[c >> 1].w, li);
            const float wbx = rdlane(w2B[c >> 1].x, li);
            const float wby = rdlane(w2B[c >> 1].y, li);
            const float wbz = rdlane(w2B[c >> 1].z, li);
            const float wbw = rdlane(w2B[c >> 1].w, li);
            const float hax = rdlane(hA[c >> 1].x, li);
            const float hay = rdlane(hA[c >> 1].y, li);
            const float haz = rdlane(hA[c >> 1].z, li);
            const float haw = rdlane(hA[c >> 1].w, li);
            const float hbx = rdlane(hB[c >> 1].x, li);
            const float hby = rdlane(hB[c >> 1].y, li);
            const float hbz = rdlane(hB[c >> 1].z, li);
            const float hbw = rdlane(hB[c >> 1].w, li);

            const float x2 = a.x * a.x, y2 = a.y * a.y;
            const float z2 = a.z * a.z, q2 = a.w * a.w;

            accNA = fmaf(a.x, hax, accNA);
            accNA = fmaf(a.y, hay, accNA);
            accNA = fmaf(a.z, haz, accNA);
            accNA = fmaf(a.w, haw, accNA);
            accNB = fmaf(a.x, hbx, accNB);
            accNB = fmaf(a.y, hby, accNB);
            accNB = fmaf(a.z, hbz, accNB);
            accNB = fmaf(a.w, hbw, accNB);
            accDA = fmaf(x2, wax, accDA);
            accDA = fmaf(y2, way, accDA);
            accDA = fmaf(z2, waz, accDA);
            accDA = fmaf(q2, waw, accDA);
            accDB = fmaf(x2, wbx, accDB);
            accDB = fmaf(y2, wby, accDB);
            accDB = fmaf(z2, wbz, accDB);
            accDB = fmaf(q2, wbw, accDB);
        }
    }

    // mask is linear in the k-sum: num *= mk, n1 *= |mk| (exact for any float mask)
    const float amk  = fabsf(mk);
    const float denA = fmaxf(sqrtf(accDA) * amk * n2vA, EPSV);
    const float denB = fmaxf(sqrtf(accDB) * amk * n2vB, EPSV);
    const size_t o = (size_t)(b * 256 + t) * 32;
    out[o + p]      = (accNA * mk) / denA;
    out[o + p + 16] = (accNB * mk) / denB;
}

extern "C" void kernel_launch(void* const* d_in, const int* in_sizes, int n_in,
                              void* d_out, int out_size, void* d_ws, size_t ws_size,
                              hipStream_t stream) {
    const float* v1      = (const float*)d_in[0];
    const float* v1_mask = (const float*)d_in[1];
    const float* v2      = (const float*)d_in[2];
    const float* w       = (const float*)d_in[3];
    float* out           = (float*)d_out;

    fullmatch_kernel<<<dim3(256), dim3(256), 0, stream>>>(v1, v1_mask, v2, w, out);
}

// Round 4
// 19.662 us; speedup vs baseline: 1.2331x; 1.0810x over previous
//
#include <hip/hip_runtime.h>
#include <cstddef>

#define EPSV 1e-8f

__device__ __forceinline__ float rdlane(float x, int s) {
    return __int_as_float(__builtin_amdgcn_readlane(__float_as_int(x), s));
}

#define GLD16(gp, lp) \
    __builtin_amdgcn_global_load_lds((const __attribute__((address_space(1))) void*)(gp), \
                                     (__attribute__((address_space(3))) void*)(lp), 16, 0, 0)

// Grid: 512 blocks = 64 v1-tiles (64 t-rows) x 8 l-pair-groups -> 2 blocks/CU,
// 8 waves/CU = 2 waves/SIMD (the R0-R2 kernels were 1/SIMD and stall-bound).
// Wave = 64 t-lanes x 1 l-pair (p, p+16) x HALF the quad-columns (dh split):
// two waves accumulate interleaved halves of the K-reduction and combine once
// through a 4KB LDS buffer. w2/h live distributed in VGPRs, broadcast via
// v_readlane with compile-time/SGPR-uniform lane selects (all loops fully
// unrolled -> static array indexing, no scratch). XCD swizzle: bid = lpg*64 +
// tile so all 8 blocks of one tile share an XCD L2.
__global__ __launch_bounds__(256, 2) void fullmatch_kernel(
    const float* __restrict__ v1,       // [16,256,512]
    const float* __restrict__ v1_mask,  // [16,256]
    const float* __restrict__ v2,       // [16,512]
    const float* __restrict__ w,        // [32,512]
    float* __restrict__ out)            // [16,256,32]
{
    const int tid  = threadIdx.x;
    const int lane = tid & 63;
    const int wv   = tid >> 6;          // 0..3
    const int lp2  = wv & 1;            // which l-pair of this block's two
    const int dh   = wv >> 1;           // K-half: quad-cols dh*16..dh*16+15 of each chunk
    const int dh16 = __builtin_amdgcn_readfirstlane(dh) * 16;  // SGPR, wave-uniform

    const int bid  = blockIdx.x;
    const int tile = bid & 63;          // xcd = tile % 8 under round-robin dispatch
    const int lpg  = bid >> 6;          // 0..7
    const int b    = tile >> 2;
    const int t0   = (tile & 3) * 64;
    const int p    = lpg * 2 + lp2;     // l = p and p+16
    const int t    = t0 + lane;

    __shared__ float v1s[2][64][128];   // 64 KB double-buffered K-chunk
    __shared__ float cmb[4][64][4];     // 4 KB partial-sum combine buffer

    const size_t v1base = (size_t)(b * 256 + t0) * 512;

    // ---- issue chunk 0 staging (async global->LDS; linear dest, pre-swizzled src) ----
    #pragma unroll
    for (int j = 0; j < 8; ++j) {
        const int r0 = wv * 16 + j * 2;           // 2 rows per issue, wave-uniform base
        const int r  = r0 + (lane >> 5);
        const int c4 = (lane & 31) ^ (r & 31);    // inverse-swizzled source col
        GLD16(v1 + v1base + (size_t)r * 512 + c4 * 4, &v1s[0][r0][0]);
    }

    // ---- per-wave w2/h register slices (distributed over 64 lanes) + n2 ----
    float4 w2A[2], w2B[2], hA[2], hB[2];
    float n2pA = 0.f, n2pB = 0.f;
    {
        const float* __restrict__ v2b = v2 + (size_t)b * 512;
        const float* __restrict__ wAp = w + (size_t)p * 512;
        const float* __restrict__ wBp = w + (size_t)(p + 16) * 512;
        #pragma unroll
        for (int q = 0; q < 2; ++q) {
            const int k4 = q * 64 + lane;         // global quad index held by this lane
            const float4 wa = *(const float4*)(wAp + k4 * 4);
            const float4 wb = *(const float4*)(wBp + k4 * 4);
            const float4 vv = *(const float4*)(v2b + k4 * 4);
            float4 sa, sb, ha, hb;
            sa.x = wa.x*wa.x; sa.y = wa.y*wa.y; sa.z = wa.z*wa.z; sa.w = wa.w*wa.w;
            sb.x = wb.x*wb.x; sb.y = wb.y*wb.y; sb.z = wb.z*wb.z; sb.w = wb.w*wb.w;
            ha.x = sa.x*vv.x; ha.y = sa.y*vv.y; ha.z = sa.z*vv.z; ha.w = sa.w*vv.w;
            hb.x = sb.x*vv.x; hb.y = sb.y*vv.y; hb.z = sb.z*vv.z; hb.w = sb.w*vv.w;
            w2A[q] = sa; w2B[q] = sb; hA[q] = ha; hB[q] = hb;
            n2pA += ha.x*vv.x + ha.y*vv.y + ha.z*vv.z + ha.w*vv.w;
            n2pB += hb.x*vv.x + hb.y*vv.y + hb.z*vv.z + hb.w*vv.w;
        }
    }
    // one-time 64-lane butterfly for n2 (12 cross-lane ops)
    #pragma unroll
    for (int m = 32; m >= 1; m >>= 1) {
        n2pA += __shfl_xor(n2pA, m, 64);
        n2pB += __shfl_xor(n2pB, m, 64);
    }

    float accNA = 0.f, accNB = 0.f, accDA = 0.f, accDB = 0.f;
    const int lm = lane & 31;

    #pragma unroll
    for (int c = 0; c < 4; ++c) {
        __syncthreads();   // buf[c&1] staged (compiler drains vmcnt before barrier)
        if (c < 3) {
            #pragma unroll
            for (int j = 0; j < 8; ++j) {
                const int r0 = wv * 16 + j * 2;
                const int r  = r0 + (lane >> 5);
                const int c4 = (lane & 31) ^ (r & 31);
                GLD16(v1 + v1base + (size_t)r * 512 + (c + 1) * 128 + c4 * 4,
                      &v1s[(c + 1) & 1][r0][0]);
            }
        }
        const float* __restrict__ row = &v1s[c & 1][lane][0];
        #pragma unroll
        for (int j = 0; j < 16; ++j) {            // FULL unroll: static indices
            const int s  = dh16 + j;              // this wave's quad-column (SGPR-uniform)
            const float4 a = *(const float4*)(row + ((s ^ lm) << 2)); // = v1 quad s of row t
            const int li = ((c & 1) << 5) + s;    // lane holding quad k4 = c*32+s
            const int q  = c >> 1;                // static after unroll

            const float wax = rdlane(w2A[q].x, li);
            const float way = rdlane(w2A[q].y, li);
            const float waz = rdlane(w2A[q].z, li);
            const float waw = rdlane(w2A[q].w, li);
            const float wbx = rdlane(w2B[q].x, li);
            const float wby = rdlane(w2B[q].y, li);
            const float wbz = rdlane(w2B[q].z, li);
            const float wbw = rdlane(w2B[q].w, li);
            const float hax = rdlane(hA[q].x, li);
            const float hay = rdlane(hA[q].y, li);
            const float haz = rdlane(hA[q].z, li);
            const float haw = rdlane(hA[q].w, li);
            const float hbx = rdlane(hB[q].x, li);
            const float hby = rdlane(hB[q].y, li);
            const float hbz = rdlane(hB[q].z, li);
            const float hbw = rdlane(hB[q].w, li);

            const float x2 = a.x * a.x, y2 = a.y * a.y;
            const float z2 = a.z * a.z, q2 = a.w * a.w;

            accNA = fmaf(a.x, hax, accNA);
            accNA = fmaf(a.y, hay, accNA);
            accNA = fmaf(a.z, haz, accNA);
            accNA = fmaf(a.w, haw, accNA);
            accNB = fmaf(a.x, hbx, accNB);
            accNB = fmaf(a.y, hby, accNB);
            accNB = fmaf(a.z, hbz, accNB);
            accNB = fmaf(a.w, hbw, accNB);
            accDA = fmaf(x2, wax, accDA);
            accDA = fmaf(y2, way, accDA);
            accDA = fmaf(z2, waz, accDA);
            accDA = fmaf(q2, waw, accDA);
            accDB = fmaf(x2, wbx, accDB);
            accDB = fmaf(y2, wby, accDB);
            accDB = fmaf(z2, wbz, accDB);
            accDB = fmaf(q2, wbw, accDB);
        }
    }

    // ---- combine the two K-halves: one LDS round-trip + barrier ----
    cmb[wv][lane][0] = accNA;
    cmb[wv][lane][1] = accNB;
    cmb[wv][lane][2] = accDA;
    cmb[wv][lane][3] = accDB;
    __syncthreads();

    if (wv < 2) {   // dh==0 waves finalize (partner wave is wv+2)
        const float4 o = *(const float4*)(&cmb[wv + 2][lane][0]);
        const float nA = accNA + o.x;
        const float nB = accNB + o.y;
        const float dA = accDA + o.z;
        const float dB = accDB + o.w;

        const float mk  = v1_mask[b * 256 + t];
        const float amk = fabsf(mk);
        const float n2vA = sqrtf(n2pA);
        const float n2vB = sqrtf(n2pB);
        const float denA = fmaxf(sqrtf(dA) * amk * n2vA, EPSV);
        const float denB = fmaxf(sqrtf(dB) * amk * n2vB, EPSV);
        const size_t oix = (size_t)(b * 256 + t) * 32;
        out[oix + p]      = (nA * mk) / denA;
        out[oix + p + 16] = (nB * mk) / denB;
    }
}

extern "C" void kernel_launch(void* const* d_in, const int* in_sizes, int n_in,
                              void* d_out, int out_size, void* d_ws, size_t ws_size,
                              hipStream_t stream) {
    const float* v1      = (const float*)d_in[0];
    const float* v1_mask = (const float*)d_in[1];
    const float* v2      = (const float*)d_in[2];
    const float* w       = (const float*)d_in[3];
    float* out           = (float*)d_out;

    fullmatch_kernel<<<dim3(512), dim3(256), 0, stream>>>(v1, v1_mask, v2, w, out);
}